// Round 16
// baseline (36386.453 us; speedup 1.0000x reference)
//
#include <hip/hip_runtime.h>
#include <hip/hip_bf16.h>

typedef unsigned int u32;
typedef unsigned short u16;
typedef unsigned long long u64;
using half2_t = __attribute__((ext_vector_type(2))) _Float16;
using half8   = __attribute__((ext_vector_type(8))) _Float16;
using f32x4   = __attribute__((ext_vector_type(4))) float;
using u32x4   = __attribute__((ext_vector_type(4))) u32;

// Problem dims
#define TT 16384
#define HDIM 2048
#define N3H 6144
#define ODIM 1000

// Workspace layout (bytes). Total = 318,785,536 (~304 MB)
#define WS_WPACK 0ull                 // 25,165,824  : W_hh packed f16 pairs
#define WS_PROG  25165824ull          // 512         : progress counters [128] u32
#define WS_IG    117440512ull         // 201,326,592 : igates f16 [T][6144]
#define WS_PAIR  318767104ull         // 8,192       : h publish packed [2][1024] u32
#define WS_NEED  318785536ull

#if __has_builtin(__builtin_amdgcn_fdot2)
__device__ __forceinline__ float fdot2u(u32 a, u32 b, float c) {
  return __builtin_amdgcn_fdot2(__builtin_bit_cast(half2_t, a),
                                __builtin_bit_cast(half2_t, b), c, false);
}
#else
__device__ __forceinline__ float fdot2u(u32 a, u32 b, float c) {
  half2_t x = __builtin_bit_cast(half2_t, a), y = __builtin_bit_cast(half2_t, b);
  return c + (float)x[0] * (float)y[0] + (float)x[1] * (float)y[1];
}
#endif

// Coherent coalesced 16B load: sc0+sc1 -> served at the device coherence
// point; each dword individually atomic (all the in-band epoch scheme needs).
__device__ __forceinline__ u32x4 poll_load16(const u32* p) {
  u32x4 r;
  asm volatile("global_load_dwordx4 %0, %1, off sc0 sc1\n\ts_waitcnt vmcnt(0)"
               : "=&v"(r) : "v"(p));
  return r;
}
// Coherent dword load at the CP.
__device__ __forceinline__ u32 cload4_cp(const u32* p) {
  u32 r;
  asm volatile("global_load_dword %0, %1, off sc0 sc1\n\ts_waitcnt vmcnt(0)"
               : "=&v"(r) : "v"(p));
  return r;
}
// Three coherent ushort loads, one RTT (single vmcnt drain). NOTE: the drain
// doubles as part of the pre-poll delay that lets publishes land before the
// first poll round (R10 vs R9/R11/R13 evidence — do not remove).
__device__ __forceinline__ void ld3_f16_cp(const _Float16* p0, const _Float16* p1,
                                           const _Float16* p2, float& a, float& b, float& c) {
  u32 ra, rb, rc;
  asm volatile("global_load_ushort %0, %3, off sc0 sc1\n\t"
               "global_load_ushort %1, %4, off sc0 sc1\n\t"
               "global_load_ushort %2, %5, off sc0 sc1\n\t"
               "s_waitcnt vmcnt(0)"
               : "=&v"(ra), "=&v"(rb), "=&v"(rc)
               : "v"(p0), "v"(p1), "v"(p2));
  a = (float)__builtin_bit_cast(_Float16, (u16)ra);
  b = (float)__builtin_bit_cast(_Float16, (u16)rb);
  c = (float)__builtin_bit_cast(_Float16, (u16)rc);
}
// Coherent 2-byte store at the CP (write-through).
__device__ __forceinline__ void st2_cp(_Float16* p, _Float16 v) {
  u32 u = (u32)__builtin_bit_cast(u16, v);
  asm volatile("global_store_short %0, %1, off sc0 sc1" :: "v"(p), "v"(u) : "memory");
}

// ---------------- init the packed publish buffers ----------------------------
// Buffer 0 (dwords 0..1023) first used at t+1=2 (epoch 1)  -> init epoch 0.
// Buffer 1 (dwords 1024..2047) first used at t+1=1 (epoch 0) -> init epoch 1.
__global__ void k_zero2(u32* p) {
  int i = blockIdx.x * 256 + threadIdx.x;  // 2048 dwords
  p[i] = (i >= 1024) ? 0x00010001u : 0u;
}
__global__ void k_zero_n(u32* p, int n) {
  int i = blockIdx.x * 256 + threadIdx.x;
  if (i < n) p[i] = 0u;
}

// ---------------- pack W_hh into per-(hrow,wave,lane) f16-pair layout --------
// (verbatim R3/R9) dword idx = hrow*3072 + c*256 + lane*4 + q ; dl=c*4+q
// g=dl/16 ; m=dl%16 ; value = (W_hh[g*2048+hrow][2*(lane*16+m)], ...+1)
__global__ __launch_bounds__(256) void k_pack(const float* __restrict__ whh,
                                              u32* __restrict__ outp) {
  u32 idx = blockIdx.x * 256 + threadIdx.x;  // < 6,291,456
  u32 hrow = idx / 3072;
  u32 rem = idx - hrow * 3072;
  u32 c = rem >> 8;
  u32 lane = (rem >> 2) & 63;
  u32 q = rem & 3;
  u32 dl = c * 4 + q;
  u32 g = dl >> 4;
  u32 m = dl & 15;
  u32 kp = lane * 16 + m;
  const float* src = whh + (size_t)(g * 2048 + hrow) * 2048 + 2 * kp;
  half2_t p;
  p[0] = (_Float16)src[0];
  p[1] = (_Float16)src[1];
  outp[idx] = __builtin_bit_cast(u32, p);
}

__device__ __forceinline__ u32 packf16(float a, float b) {
  half2_t p;
  p[0] = (_Float16)a;
  p[1] = (_Float16)b;
  return __builtin_bit_cast(u32, p);
}

// ---------------- fused coop kernel: 256 WGs x 512 thr -----------------------
// WG 0..127  : GRU scan, rows r0 = wg*16 + 2v per wave v.
// WG 128..255: igates GEMM helpers (unchanged from R15).
// R16 change (single, isolated): h exchange packed 2 rows/dword
// {f15_r1|e | f15_r0|e}; publish = 1 atomic dword per wave; poll = 256
// threads x dwordx4 covering all 1024 dwords (bytes AND requests halve).
// Epoch bit e=((t+1)>>1)&1 distinguishes t+1 from t-1 (the only stale value
// observable under the double-buffer lead bound).
__global__ __launch_bounds__(512) void k_fused(const uint4* __restrict__ wpack,
                                               const _Float16* __restrict__ ig,
                                               const float* __restrict__ bias_n,
                                               u32* pair,
                                               const float* __restrict__ X,
                                               const float* __restrict__ Wih,
                                               const float* __restrict__ bias,
                                               u32* prog) {
  __shared__ __align__(16) u32 smem[4096];  // 16KB: scan uses 1280, gemm 4096
  const int tid = threadIdx.x;

  if (blockIdx.x < 128) {
    // ======================= SCAN ==========================================
    u32* lds_h = smem;  // 1024 f16-pair dwords + pad 4/16
    const int l = tid & 63, v = tid >> 6;
    const int wg = blockIdx.x;
    const int r0 = wg * 16 + v * 2;
    const int my_row = r0 + (l & 1);

    u32 wdwA[48], wdwB[48];
    {
      const uint4* wpA = wpack + (size_t)r0 * 768 + l;
      const uint4* wpB = wpA + 768;  // row r0+1
#pragma unroll
      for (int c = 0; c < 12; ++c) {
        uint4 a = wpA[(size_t)c * 64];
        wdwA[c * 4] = a.x; wdwA[c * 4 + 1] = a.y; wdwA[c * 4 + 2] = a.z; wdwA[c * 4 + 3] = a.w;
      }
#pragma unroll
      for (int c = 0; c < 12; ++c) {
        uint4 b = wpB[(size_t)c * 64];
        wdwB[c * 4] = b.x; wdwB[c * 4 + 1] = b.y; wdwB[c * 4 + 2] = b.z; wdwB[c * 4 + 3] = b.w;
      }
    }
    const float bn = bias_n[my_row];
    float hm = 0.f;  // fp32 master state for my_row (valid in lanes 0,1)
    u32 hreg[16];
#pragma unroll
    for (int m = 0; m < 16; ++m) hreg[m] = 0;  // h(0) = 0

    int ready_blk = 0;
    {  // gate igates m-block 0, then load row 0
      for (;;) {
        u32 c = cload4_cp(prog);
        if (c >= 48u) break;
        __builtin_amdgcn_s_sleep(8);
      }
      ready_blk = 1;
    }
    float ig0, ig1, ig2;
    ld3_f16_cp(ig + my_row, ig + 2048 + my_row, ig + 4096 + my_row, ig0, ig1, ig2);

    for (int t = 0; t < TT; ++t) {
      float igr = ig0, igz = ig1, ign = ig2;
      float a0 = 0.f, a1 = 0.f, a2 = 0.f, a3 = 0.f, a4 = 0.f, a5 = 0.f;
      float b0 = 0.f, b1 = 0.f, b2 = 0.f, b3 = 0.f, b4 = 0.f, b5 = 0.f;
#pragma unroll
      for (int m = 0; m < 16; m += 2) {
        a0 = fdot2u(wdwA[m],          hreg[m],     a0);
        b0 = fdot2u(wdwA[m + 1],      hreg[m + 1], b0);
        a1 = fdot2u(wdwA[16 + m],     hreg[m],     a1);
        b1 = fdot2u(wdwA[16 + m + 1], hreg[m + 1], b1);
        a2 = fdot2u(wdwA[32 + m],     hreg[m],     a2);
        b2 = fdot2u(wdwA[32 + m + 1], hreg[m + 1], b2);
        a3 = fdot2u(wdwB[m],          hreg[m],     a3);
        b3 = fdot2u(wdwB[m + 1],      hreg[m + 1], b3);
        a4 = fdot2u(wdwB[16 + m],     hreg[m],     a4);
        b4 = fdot2u(wdwB[16 + m + 1], hreg[m + 1], b4);
        a5 = fdot2u(wdwB[32 + m],     hreg[m],     a5);
        b5 = fdot2u(wdwB[32 + m + 1], hreg[m + 1], b5);
      }
      float s0 = a0 + b0, s1 = a1 + b1, s2 = a2 + b2;
      float s3 = a3 + b3, s4 = a4 + b4, s5 = a5 + b5;
#pragma unroll
      for (int off = 1; off < 64; off <<= 1) {
        s0 += __shfl_xor(s0, off, 64);
        s1 += __shfl_xor(s1, off, 64);
        s2 += __shfl_xor(s2, off, 64);
        s3 += __shfl_xor(s3, off, 64);
        s4 += __shfl_xor(s4, off, 64);
        s5 += __shfl_xor(s5, off, 64);
      }
      u32* pdst = pair + (((t + 1) & 1) << 10);
      const u32 emask = (((t + 1) >> 1) & 1u) * 0x00010001u;
      u32 hb = 0;
      if (l < 2) {
        float sr = l ? s3 : s0, sz = l ? s4 : s1, sn = l ? s5 : s2;
        float r = 1.f / (1.f + __expf(-(igr + sr)));
        float z = 1.f / (1.f + __expf(-(igz + sz)));
        float nx = ign + r * (sn + bn);
        float e = __expf(-2.f * nx);
        float n = (1.f - e) / (1.f + e);
        hm = n + z * (hm - n);
        // f15: round-to-nearest f16 with LSB dropped (|h|<=1 -> no overflow)
        hb = ((u32)__builtin_bit_cast(u16, (_Float16)hm) + 1u) & 0xFFFEu;
      }
      u32 hb1 = __shfl(hb, 1, 64);  // row r0+1's f15 -> lane 0
      if (l == 0)
        __hip_atomic_store(pdst + (r0 >> 1), hb | (hb1 << 16) | emask,
                           __ATOMIC_RELAXED, __HIP_MEMORY_SCOPE_AGENT);
      if (t == TT - 1) break;
      {  // gate + prefetch next igates row (CP loads; drain = pre-poll delay)
        int nb = (t + 1) >> 7;
        if (nb >= ready_blk) {
          const u32* pb = prog + nb;
          for (;;) {
            u32 c = cload4_cp(pb);
            if (c >= 48u) break;
            __builtin_amdgcn_s_sleep(8);
          }
          ready_blk = nb + 1;
        }
        const _Float16* igp = ig + (size_t)(t + 1) * N3H;
        ld3_f16_cp(igp + my_row, igp + 2048 + my_row, igp + 4096 + my_row, ig0, ig1, ig2);
      }
      // poll: 256 threads x dwordx4 cover all 1024 packed dwords.
      u32x4 d;
      d[0] = 0; d[1] = 0; d[2] = 0; d[3] = 0;
      if (tid < 256) {
        const u32* pp = pdst + 4 * tid;
        __builtin_amdgcn_s_sleep(10);  // pre-poll delay (R15 win — keep)
        for (;;) {
          d = poll_load16(pp);
          u32 bad = ((d[0] ^ emask) | (d[1] ^ emask) | (d[2] ^ emask) |
                     (d[3] ^ emask)) & 0x00010001u;
          if (!bad) break;
          __builtin_amdgcn_s_sleep(2);
        }
      }
      __syncthreads();  // all local waves done reading lds_h of prev step
      if (tid < 256) {   // unpack: zero epoch bits -> f15 pairs, padded LDS
        u32* dst = lds_h + 4 * tid + ((tid >> 2) << 2);
        dst[0] = d[0] & 0xFFFEFFFEu;
        dst[1] = d[1] & 0xFFFEFFFEu;
        dst[2] = d[2] & 0xFFFEFFFEu;
        dst[3] = d[3] & 0xFFFEFFFEu;
      }
      __syncthreads();
#pragma unroll
      for (int i = 0; i < 4; ++i) {
        uint4 vv = *(const uint4*)(lds_h + l * 20 + i * 4);
        hreg[i * 4] = vv.x; hreg[i * 4 + 1] = vv.y; hreg[i * 4 + 2] = vv.z; hreg[i * 4 + 3] = vv.w;
      }
    }
  } else {
    // ======================= GEMM HELPERS ===================================
    _Float16* As = (_Float16*)smem;           // [128][32] f16 = 8KB
    _Float16* Bs = (_Float16*)(smem + 2048);  // [128][32] f16 = 8KB
    const int hid = blockIdx.x - 128;
    const int l = tid & 63, w = tid >> 6;
    const int wr = w >> 2, wc = w & 3;        // 2x4 wave grid
    const int srow = tid >> 2;                // 0..127
    const int scol = (tid & 3) << 3;          // 0,8,16,24

    for (int tile = hid; tile < 6144; tile += 128) {
      const int mb = tile / 48, nb = tile - mb * 48;
      const int m0 = mb * 128, n0 = nb * 128;
      f32x4 acc[4][2] = {};

      for (int k0 = 0; k0 < HDIM; k0 += 32) {
        __syncthreads();
        const float* ap = X + (size_t)(m0 + srow) * HDIM + k0 + scol;
        const float* bp = Wih + (size_t)(n0 + srow) * HDIM + k0 + scol;
        float4 aL = *(const float4*)ap, aH = *(const float4*)(ap + 4);
        float4 bL = *(const float4*)bp, bH = *(const float4*)(bp + 4);
        uint4 av4 = make_uint4(packf16(aL.x, aL.y), packf16(aL.z, aL.w),
                               packf16(aH.x, aH.y), packf16(aH.z, aH.w));
        uint4 bv4 = make_uint4(packf16(bL.x, bL.y), packf16(bL.z, bL.w),
                               packf16(bH.x, bH.y), packf16(bH.z, bH.w));
        *(uint4*)(As + srow * 32 + scol) = av4;
        *(uint4*)(Bs + srow * 32 + scol) = bv4;
        __syncthreads();
        half8 av[4], bv[2];
#pragma unroll
        for (int mi = 0; mi < 4; ++mi)
          av[mi] = *(const half8*)(As + (wr * 64 + mi * 16 + (l & 15)) * 32 + (l >> 4) * 8);
#pragma unroll
        for (int ni = 0; ni < 2; ++ni)
          bv[ni] = *(const half8*)(Bs + (wc * 32 + ni * 16 + (l & 15)) * 32 + (l >> 4) * 8);
#pragma unroll
        for (int mi = 0; mi < 4; ++mi)
#pragma unroll
          for (int ni = 0; ni < 2; ++ni)
            acc[mi][ni] = __builtin_amdgcn_mfma_f32_16x16x32_f16(av[mi], bv[ni], acc[mi][ni], 0, 0, 0);
      }
      _Float16* Cout = (_Float16*)ig;
#pragma unroll
      for (int ni = 0; ni < 2; ++ni) {
        int col = n0 + wc * 32 + ni * 16 + (l & 15);
        float bb = bias[col];
#pragma unroll
        for (int mi = 0; mi < 4; ++mi) {
          int rbase = m0 + wr * 64 + mi * 16 + (l >> 4) * 4;
#pragma unroll
          for (int r = 0; r < 4; ++r)
            st2_cp(Cout + (size_t)(rbase + r) * N3H + col,
                   (_Float16)(acc[mi][ni][r] + bb));
        }
      }
      asm volatile("s_waitcnt vmcnt(0)" ::: "memory");  // data at CP
      __syncthreads();                                   // all threads drained
      if (tid == 0)
        __hip_atomic_fetch_add(prog + mb, 1u, __ATOMIC_RELAXED,
                               __HIP_MEMORY_SCOPE_AGENT);
    }
  }
}

// ---------------- final projection: out = w_out @ h_final + b_out + b_extra --
// h_final = packed buffer 0 (TT even): dword j = rows {2j lo, 2j+1 hi} f15;
// epoch bits masked off.
__global__ __launch_bounds__(256) void k_out(const float* __restrict__ wout,
                                             const float* __restrict__ bout,
                                             const float* __restrict__ bextra,
                                             const u32* __restrict__ hp,
                                             float* __restrict__ out) {
  const int l = threadIdx.x & 63;
  const int o = blockIdx.x * 4 + (threadIdx.x >> 6);
  if (o >= ODIM) return;
  const float* wr = wout + (size_t)o * HDIM;
  float acc = 0.f;
#pragma unroll
  for (int i = 0; i < 4; ++i) {
    int j = i * 256 + l * 4;  // dword base; covers rows 2j..2j+7
    uint4 hd = *(const uint4*)(hp + j);
    float4 w0 = *(const float4*)(wr + 2 * j);
    float4 w1 = *(const float4*)(wr + 2 * j + 4);
    acc += w0.x * (float)__builtin_bit_cast(_Float16, (u16)(hd.x & 0xFFFEu));
    acc += w0.y * (float)__builtin_bit_cast(_Float16, (u16)((hd.x >> 16) & 0xFFFEu));
    acc += w0.z * (float)__builtin_bit_cast(_Float16, (u16)(hd.y & 0xFFFEu));
    acc += w0.w * (float)__builtin_bit_cast(_Float16, (u16)((hd.y >> 16) & 0xFFFEu));
    acc += w1.x * (float)__builtin_bit_cast(_Float16, (u16)(hd.z & 0xFFFEu));
    acc += w1.y * (float)__builtin_bit_cast(_Float16, (u16)((hd.z >> 16) & 0xFFFEu));
    acc += w1.z * (float)__builtin_bit_cast(_Float16, (u16)(hd.w & 0xFFFEu));
    acc += w1.w * (float)__builtin_bit_cast(_Float16, (u16)((hd.w >> 16) & 0xFFFEu));
  }
#pragma unroll
  for (int off = 1; off < 64; off <<= 1) acc += __shfl_xor(acc, off, 64);
  if (l == 0) out[o] = acc + bout[o] + bextra[o];
}

// sentinel if workspace too small: absmax ~= 1e6 + ws_size_in_MB (debug channel)
__global__ void k_dbg(float* out, float v) {
  int i = blockIdx.x * 256 + threadIdx.x;
  if (i < ODIM) out[i] = v;
}

extern "C" void kernel_launch(void* const* d_in, const int* in_sizes, int n_in,
                              void* d_out, int out_size, void* d_ws, size_t ws_size,
                              hipStream_t stream) {
  const float* x      = (const float*)d_in[0];
  const float* wih    = (const float*)d_in[1];
  const float* whh    = (const float*)d_in[2];
  const float* bias   = (const float*)d_in[3];
  const float* bias_n = (const float*)d_in[4];
  const float* wout   = (const float*)d_in[5];
  const float* bout   = (const float*)d_in[6];
  const float* bextra = (const float*)d_in[7];
  float* out = (float*)d_out;

  if (ws_size < WS_NEED) {
    k_dbg<<<4, 256, 0, stream>>>(out, 1.0e6f + (float)(ws_size / 1048576ull));
    return;
  }

  char* ws = (char*)d_ws;
  u32*      wpack = (u32*)(ws + WS_WPACK);
  u32*      prog  = (u32*)(ws + WS_PROG);
  _Float16* igb   = (_Float16*)(ws + WS_IG);
  u32*      pairb = (u32*)(ws + WS_PAIR);

  k_zero2<<<8, 256, 0, stream>>>(pairb);
  k_zero_n<<<1, 256, 0, stream>>>(prog, 128);
  k_pack<<<24576, 256, 0, stream>>>(whh, wpack);

  const uint4* wpc = (const uint4*)wpack;
  const _Float16* igc = igb;
  void* kargs[] = {(void*)&wpc, (void*)&igc, (void*)&bias_n, (void*)&pairb,
                   (void*)&x, (void*)&wih, (void*)&bias, (void*)&prog};
  hipLaunchCooperativeKernel(k_fused, dim3(256), dim3(512), kargs, 0, stream);

  k_out<<<250, 256, 0, stream>>>(wout, bout, bextra, pairb, out);
}

// Round 17
// 34582.831 us; speedup vs baseline: 1.0522x; 1.0522x over previous
//
#include <hip/hip_runtime.h>
#include <hip/hip_bf16.h>

typedef unsigned int u32;
typedef unsigned short u16;
typedef unsigned long long u64;
using half2_t = __attribute__((ext_vector_type(2))) _Float16;
using half8   = __attribute__((ext_vector_type(8))) _Float16;
using f32x4   = __attribute__((ext_vector_type(4))) float;
using u32x4   = __attribute__((ext_vector_type(4))) u32;

// Problem dims
#define TT 16384
#define HDIM 2048
#define N3H 6144
#define ODIM 1000

// Workspace layout (bytes). Total = 318,785,536 (~304 MB)
#define WS_WPACK 0ull                 // 25,165,824  : W_hh packed f16 pairs
#define WS_PROG  25165824ull          // 512         : progress counters [128] u32
#define WS_IG    117440512ull         // 201,326,592 : igates f16 [T][6144]
#define WS_PAIR  318767104ull         // 16,384      : h publish {tag16|f16} [2][2048] u32
#define WS_NEED  318785536ull

#if __has_builtin(__builtin_amdgcn_fdot2)
__device__ __forceinline__ float fdot2u(u32 a, u32 b, float c) {
  return __builtin_amdgcn_fdot2(__builtin_bit_cast(half2_t, a),
                                __builtin_bit_cast(half2_t, b), c, false);
}
#else
__device__ __forceinline__ float fdot2u(u32 a, u32 b, float c) {
  half2_t x = __builtin_bit_cast(half2_t, a), y = __builtin_bit_cast(half2_t, b);
  return c + (float)x[0] * (float)y[0] + (float)x[1] * (float)y[1];
}
#endif

// Coherent coalesced 16B load: sc0+sc1 -> served at the device coherence
// point; each dword individually atomic (all the in-band tag scheme needs).
__device__ __forceinline__ u32x4 poll_load16(const u32* p) {
  u32x4 r;
  asm volatile("global_load_dwordx4 %0, %1, off sc0 sc1\n\ts_waitcnt vmcnt(0)"
               : "=&v"(r) : "v"(p));
  return r;
}
// Coherent dword load at the CP.
__device__ __forceinline__ u32 cload4_cp(const u32* p) {
  u32 r;
  asm volatile("global_load_dword %0, %1, off sc0 sc1\n\ts_waitcnt vmcnt(0)"
               : "=&v"(r) : "v"(p));
  return r;
}
// Three coherent ushort loads, one RTT (single vmcnt drain). NOTE: the drain
// doubles as part of the pre-poll delay that lets publishes land before the
// first poll round (R10 vs R9/R11/R13 evidence — do not remove).
__device__ __forceinline__ void ld3_f16_cp(const _Float16* p0, const _Float16* p1,
                                           const _Float16* p2, float& a, float& b, float& c) {
  u32 ra, rb, rc;
  asm volatile("global_load_ushort %0, %3, off sc0 sc1\n\t"
               "global_load_ushort %1, %4, off sc0 sc1\n\t"
               "global_load_ushort %2, %5, off sc0 sc1\n\t"
               "s_waitcnt vmcnt(0)"
               : "=&v"(ra), "=&v"(rb), "=&v"(rc)
               : "v"(p0), "v"(p1), "v"(p2));
  a = (float)__builtin_bit_cast(_Float16, (u16)ra);
  b = (float)__builtin_bit_cast(_Float16, (u16)rb);
  c = (float)__builtin_bit_cast(_Float16, (u16)rc);
}
// Coherent 2-byte store at the CP (write-through).
__device__ __forceinline__ void st2_cp(_Float16* p, _Float16 v) {
  u32 u = (u32)__builtin_bit_cast(u16, v);
  asm volatile("global_store_short %0, %1, off sc0 sc1" :: "v"(p), "v"(u) : "memory");
}

// ---------------- zero helpers (every launch: clears stale tags/counters) ----
__global__ void k_zero(u32* p) {
  p[blockIdx.x * 256 + threadIdx.x] = 0u;  // pair: 4096 dwords
}
__global__ void k_zero_n(u32* p, int n) {
  int i = blockIdx.x * 256 + threadIdx.x;
  if (i < n) p[i] = 0u;
}

// ---------------- pack W_hh into per-(hrow,wave,lane) f16-pair layout --------
// (verbatim R3/R9) dword idx = hrow*3072 + c*256 + lane*4 + q ; dl=c*4+q
// g=dl/16 ; m=dl%16 ; value = (W_hh[g*2048+hrow][2*(lane*16+m)], ...+1)
__global__ __launch_bounds__(256) void k_pack(const float* __restrict__ whh,
                                              u32* __restrict__ outp) {
  u32 idx = blockIdx.x * 256 + threadIdx.x;  // < 6,291,456
  u32 hrow = idx / 3072;
  u32 rem = idx - hrow * 3072;
  u32 c = rem >> 8;
  u32 lane = (rem >> 2) & 63;
  u32 q = rem & 3;
  u32 dl = c * 4 + q;
  u32 g = dl >> 4;
  u32 m = dl & 15;
  u32 kp = lane * 16 + m;
  const float* src = whh + (size_t)(g * 2048 + hrow) * 2048 + 2 * kp;
  half2_t p;
  p[0] = (_Float16)src[0];
  p[1] = (_Float16)src[1];
  outp[idx] = __builtin_bit_cast(u32, p);
}

__device__ __forceinline__ u32 packf16(float a, float b) {
  half2_t p;
  p[0] = (_Float16)a;
  p[1] = (_Float16)b;
  return __builtin_bit_cast(u32, p);
}

// ---------------- fused coop kernel: 256 WGs x 512 thr -----------------------
// WG 0..127  : GRU scan (R9 core), rows r0 = wg*16 + 2v per wave v.
// WG 128..255: igates GEMM helpers. Stores via sc0sc1; after each tile:
//   vmcnt(0) drain -> barrier -> atomicAdd(prog[mblock]). Scan gates igate
//   reads on prog[mblock]==48 and reads them sc0sc1 (always CP-fresh).
// Session-optimal config (R15): pre-poll backoff s_sleep(10) so publishes
// land before the first poll round (first-poll success = no retry storm).
__global__ __launch_bounds__(512) void k_fused(const uint4* __restrict__ wpack,
                                               const _Float16* __restrict__ ig,
                                               const float* __restrict__ bias_n,
                                               u32* pair,
                                               const float* __restrict__ X,
                                               const float* __restrict__ Wih,
                                               const float* __restrict__ bias,
                                               u32* prog) {
  __shared__ __align__(16) u32 smem[4096];  // 16KB: scan uses 1280, gemm 4096
  const int tid = threadIdx.x;

  if (blockIdx.x < 128) {
    // ======================= SCAN (R9/R10 core) =============================
    u32* lds_h = smem;  // 1024 f16-pair dwords + pad 4/16
    const int l = tid & 63, v = tid >> 6;
    const int wg = blockIdx.x;
    const int r0 = wg * 16 + v * 2;
    const int my_row = r0 + (l & 1);

    u32 wdwA[48], wdwB[48];
    {
      const uint4* wpA = wpack + (size_t)r0 * 768 + l;
      const uint4* wpB = wpA + 768;  // row r0+1
#pragma unroll
      for (int c = 0; c < 12; ++c) {
        uint4 a = wpA[(size_t)c * 64];
        wdwA[c * 4] = a.x; wdwA[c * 4 + 1] = a.y; wdwA[c * 4 + 2] = a.z; wdwA[c * 4 + 3] = a.w;
      }
#pragma unroll
      for (int c = 0; c < 12; ++c) {
        uint4 b = wpB[(size_t)c * 64];
        wdwB[c * 4] = b.x; wdwB[c * 4 + 1] = b.y; wdwB[c * 4 + 2] = b.z; wdwB[c * 4 + 3] = b.w;
      }
    }
    const float bn = bias_n[my_row];
    float hm = 0.f;  // fp32 master state for my_row (valid in lanes 0,1)
    u32 hreg[16];
#pragma unroll
    for (int m = 0; m < 16; ++m) hreg[m] = 0;  // h(0) = 0

    int ready_blk = 0;
    {  // gate igates m-block 0, then load row 0
      for (;;) {
        u32 c = cload4_cp(prog);
        if (c >= 48u) break;
        __builtin_amdgcn_s_sleep(8);
      }
      ready_blk = 1;
    }
    float ig0, ig1, ig2;
    ld3_f16_cp(ig + my_row, ig + 2048 + my_row, ig + 4096 + my_row, ig0, ig1, ig2);

    for (int t = 0; t < TT; ++t) {
      float igr = ig0, igz = ig1, ign = ig2;
      float a0 = 0.f, a1 = 0.f, a2 = 0.f, a3 = 0.f, a4 = 0.f, a5 = 0.f;
      float b0 = 0.f, b1 = 0.f, b2 = 0.f, b3 = 0.f, b4 = 0.f, b5 = 0.f;
#pragma unroll
      for (int m = 0; m < 16; m += 2) {
        a0 = fdot2u(wdwA[m],          hreg[m],     a0);
        b0 = fdot2u(wdwA[m + 1],      hreg[m + 1], b0);
        a1 = fdot2u(wdwA[16 + m],     hreg[m],     a1);
        b1 = fdot2u(wdwA[16 + m + 1], hreg[m + 1], b1);
        a2 = fdot2u(wdwA[32 + m],     hreg[m],     a2);
        b2 = fdot2u(wdwA[32 + m + 1], hreg[m + 1], b2);
        a3 = fdot2u(wdwB[m],          hreg[m],     a3);
        b3 = fdot2u(wdwB[m + 1],      hreg[m + 1], b3);
        a4 = fdot2u(wdwB[16 + m],     hreg[m],     a4);
        b4 = fdot2u(wdwB[16 + m + 1], hreg[m + 1], b4);
        a5 = fdot2u(wdwB[32 + m],     hreg[m],     a5);
        b5 = fdot2u(wdwB[32 + m + 1], hreg[m + 1], b5);
      }
      float s0 = a0 + b0, s1 = a1 + b1, s2 = a2 + b2;
      float s3 = a3 + b3, s4 = a4 + b4, s5 = a5 + b5;
#pragma unroll
      for (int off = 1; off < 64; off <<= 1) {
        s0 += __shfl_xor(s0, off, 64);
        s1 += __shfl_xor(s1, off, 64);
        s2 += __shfl_xor(s2, off, 64);
        s3 += __shfl_xor(s3, off, 64);
        s4 += __shfl_xor(s4, off, 64);
        s5 += __shfl_xor(s5, off, 64);
      }
      u32* pdst = pair + (((t + 1) & 1) << 11);
      u32 pk = 0;
      if (l < 2) {
        float sr = l ? s3 : s0, sz = l ? s4 : s1, sn = l ? s5 : s2;
        float r = 1.f / (1.f + __expf(-(igr + sr)));
        float z = 1.f / (1.f + __expf(-(igz + sz)));
        float nx = ign + r * (sn + bn);
        float e = __expf(-2.f * nx);
        float n = (1.f - e) / (1.f + e);
        hm = n + z * (hm - n);
        pk = ((u32)(t + 1) << 16) | (u32)__builtin_bit_cast(u16, (_Float16)hm);
      }
      u32 pk1 = __shfl(pk, 1, 64);  // row r0+1's packed dword -> lane 0
      if (l == 0)
        __hip_atomic_store((u64*)(pdst + r0), (u64)pk | ((u64)pk1 << 32),
                           __ATOMIC_RELAXED, __HIP_MEMORY_SCOPE_AGENT);
      if (t == TT - 1) break;
      {  // gate + prefetch next igates row (CP loads; drain = pre-poll delay)
        int nb = (t + 1) >> 7;
        if (nb >= ready_blk) {
          const u32* pb = prog + nb;
          for (;;) {
            u32 c = cload4_cp(pb);
            if (c >= 48u) break;
            __builtin_amdgcn_s_sleep(8);
          }
          ready_blk = nb + 1;
        }
        const _Float16* igp = ig + (size_t)(t + 1) * N3H;
        ld3_f16_cp(igp + my_row, igp + 2048 + my_row, igp + 4096 + my_row, ig0, ig1, ig2);
      }
      // poll own 4 rows; longer initial backoff so first round succeeds.
      const u32 tgt = (u32)(t + 1) << 16;
      const u32* pp = pdst + 4 * tid;
      __builtin_amdgcn_s_sleep(10);  // pre-poll delay (R15 win)
      u32x4 d;
      for (;;) {
        d = poll_load16(pp);
        u32 bad = ((d[0] ^ tgt) | (d[1] ^ tgt) | (d[2] ^ tgt) | (d[3] ^ tgt)) & 0xFFFF0000u;
        if (!bad) break;
        __builtin_amdgcn_s_sleep(2);
      }
      __syncthreads();  // all local waves done reading lds_h of prev step
      u32 p0 = (d[0] & 0xFFFFu) | (d[1] << 16);
      u32 p1 = (d[2] & 0xFFFFu) | (d[3] << 16);
      u32* dst = lds_h + 2 * tid + ((tid >> 3) << 2);  // pad 4 dwords per 16
      dst[0] = p0;
      dst[1] = p1;
      __syncthreads();
#pragma unroll
      for (int i = 0; i < 4; ++i) {
        uint4 vv = *(const uint4*)(lds_h + l * 20 + i * 4);
        hreg[i * 4] = vv.x; hreg[i * 4 + 1] = vv.y; hreg[i * 4 + 2] = vv.z; hreg[i * 4 + 3] = vv.w;
      }
    }
  } else {
    // ======================= GEMM HELPERS ===================================
    _Float16* As = (_Float16*)smem;           // [128][32] f16 = 8KB
    _Float16* Bs = (_Float16*)(smem + 2048);  // [128][32] f16 = 8KB
    const int hid = blockIdx.x - 128;
    const int l = tid & 63, w = tid >> 6;
    const int wr = w >> 2, wc = w & 3;        // 2x4 wave grid
    const int srow = tid >> 2;                // 0..127
    const int scol = (tid & 3) << 3;          // 0,8,16,24

    for (int tile = hid; tile < 6144; tile += 128) {
      const int mb = tile / 48, nb = tile - mb * 48;
      const int m0 = mb * 128, n0 = nb * 128;
      f32x4 acc[4][2] = {};

      for (int k0 = 0; k0 < HDIM; k0 += 32) {
        __syncthreads();
        const float* ap = X + (size_t)(m0 + srow) * HDIM + k0 + scol;
        const float* bp = Wih + (size_t)(n0 + srow) * HDIM + k0 + scol;
        float4 aL = *(const float4*)ap, aH = *(const float4*)(ap + 4);
        float4 bL = *(const float4*)bp, bH = *(const float4*)(bp + 4);
        uint4 av4 = make_uint4(packf16(aL.x, aL.y), packf16(aL.z, aL.w),
                               packf16(aH.x, aH.y), packf16(aH.z, aH.w));
        uint4 bv4 = make_uint4(packf16(bL.x, bL.y), packf16(bL.z, bL.w),
                               packf16(bH.x, bH.y), packf16(bH.z, bH.w));
        *(uint4*)(As + srow * 32 + scol) = av4;
        *(uint4*)(Bs + srow * 32 + scol) = bv4;
        __syncthreads();
        half8 av[4], bv[2];
#pragma unroll
        for (int mi = 0; mi < 4; ++mi)
          av[mi] = *(const half8*)(As + (wr * 64 + mi * 16 + (l & 15)) * 32 + (l >> 4) * 8);
#pragma unroll
        for (int ni = 0; ni < 2; ++ni)
          bv[ni] = *(const half8*)(Bs + (wc * 32 + ni * 16 + (l & 15)) * 32 + (l >> 4) * 8);
#pragma unroll
        for (int mi = 0; mi < 4; ++mi)
#pragma unroll
          for (int ni = 0; ni < 2; ++ni)
            acc[mi][ni] = __builtin_amdgcn_mfma_f32_16x16x32_f16(av[mi], bv[ni], acc[mi][ni], 0, 0, 0);
      }
      _Float16* Cout = (_Float16*)ig;
#pragma unroll
      for (int ni = 0; ni < 2; ++ni) {
        int col = n0 + wc * 32 + ni * 16 + (l & 15);
        float bb = bias[col];
#pragma unroll
        for (int mi = 0; mi < 4; ++mi) {
          int rbase = m0 + wr * 64 + mi * 16 + (l >> 4) * 4;
#pragma unroll
          for (int r = 0; r < 4; ++r)
            st2_cp(Cout + (size_t)(rbase + r) * N3H + col,
                   (_Float16)(acc[mi][ni][r] + bb));
        }
      }
      asm volatile("s_waitcnt vmcnt(0)" ::: "memory");  // data at CP
      __syncthreads();                                   // all threads drained
      if (tid == 0)
        __hip_atomic_fetch_add(prog + mb, 1u, __ATOMIC_RELAXED,
                               __HIP_MEMORY_SCOPE_AGENT);
    }
  }
}

// ---------------- final projection: out = w_out @ h_final + b_out + b_extra --
// h_final is in pair buffer 0 (TT even), f16 in low 16 bits of each dword.
__global__ __launch_bounds__(256) void k_out(const float* __restrict__ wout,
                                             const float* __restrict__ bout,
                                             const float* __restrict__ bextra,
                                             const u32* __restrict__ hp,
                                             float* __restrict__ out) {
  const int l = threadIdx.x & 63;
  const int o = blockIdx.x * 4 + (threadIdx.x >> 6);
  if (o >= ODIM) return;
  const float* wr = wout + (size_t)o * HDIM;
  float acc = 0.f;
#pragma unroll
  for (int i = 0; i < 8; ++i) {
    int k4 = i * 256 + l * 4;
    uint4 hd = *(const uint4*)(hp + k4);
    float4 wv = *(const float4*)(wr + k4);
    acc += wv.x * (float)__builtin_bit_cast(_Float16, (u16)(hd.x & 0xFFFFu));
    acc += wv.y * (float)__builtin_bit_cast(_Float16, (u16)(hd.y & 0xFFFFu));
    acc += wv.z * (float)__builtin_bit_cast(_Float16, (u16)(hd.z & 0xFFFFu));
    acc += wv.w * (float)__builtin_bit_cast(_Float16, (u16)(hd.w & 0xFFFFu));
  }
#pragma unroll
  for (int off = 1; off < 64; off <<= 1) acc += __shfl_xor(acc, off, 64);
  if (l == 0) out[o] = acc + bout[o] + bextra[o];
}

// sentinel if workspace too small: absmax ~= 1e6 + ws_size_in_MB (debug channel)
__global__ void k_dbg(float* out, float v) {
  int i = blockIdx.x * 256 + threadIdx.x;
  if (i < ODIM) out[i] = v;
}

extern "C" void kernel_launch(void* const* d_in, const int* in_sizes, int n_in,
                              void* d_out, int out_size, void* d_ws, size_t ws_size,
                              hipStream_t stream) {
  const float* x      = (const float*)d_in[0];
  const float* wih    = (const float*)d_in[1];
  const float* whh    = (const float*)d_in[2];
  const float* bias   = (const float*)d_in[3];
  const float* bias_n = (const float*)d_in[4];
  const float* wout   = (const float*)d_in[5];
  const float* bout   = (const float*)d_in[6];
  const float* bextra = (const float*)d_in[7];
  float* out = (float*)d_out;

  if (ws_size < WS_NEED) {
    k_dbg<<<4, 256, 0, stream>>>(out, 1.0e6f + (float)(ws_size / 1048576ull));
    return;
  }

  char* ws = (char*)d_ws;
  u32*      wpack = (u32*)(ws + WS_WPACK);
  u32*      prog  = (u32*)(ws + WS_PROG);
  _Float16* igb   = (_Float16*)(ws + WS_IG);
  u32*      pairb = (u32*)(ws + WS_PAIR);

  k_zero<<<16, 256, 0, stream>>>(pairb);
  k_zero_n<<<1, 256, 0, stream>>>(prog, 128);
  k_pack<<<24576, 256, 0, stream>>>(whh, wpack);

  const uint4* wpc = (const uint4*)wpack;
  const _Float16* igc = igb;
  void* kargs[] = {(void*)&wpc, (void*)&igc, (void*)&bias_n, (void*)&pairb,
                   (void*)&x, (void*)&wih, (void*)&bias, (void*)&prog};
  hipLaunchCooperativeKernel(k_fused, dim3(256), dim3(512), kargs, 0, stream);

  k_out<<<250, 256, 0, stream>>>(wout, bout, bextra, pairb, out);
}